// Round 9
// baseline (450.750 us; speedup 1.0000x reference)
//
#include <hip/hip_runtime.h>
#include <cstddef>

#define N_NODES 100000
#define N_EDGES 1600000
#define D 256

typedef short          s16x8 __attribute__((ext_vector_type(8)));
typedef unsigned short u16x8 __attribute__((ext_vector_type(8)));
typedef float          f32x4 __attribute__((ext_vector_type(4)));
typedef float          f32x8 __attribute__((ext_vector_type(8)));

__device__ __forceinline__ unsigned short f2bf(float f) {
    unsigned int u = __float_as_uint(f);
    unsigned int r = (u + 0x7fffu + ((u >> 16) & 1u)) >> 16;   // RNE
    return (unsigned short)r;
}
__device__ __forceinline__ float bf2f(unsigned short u) {
    return __uint_as_float(((unsigned int)u) << 16);
}

// ---------------------------------------------------------------------------
// Workspace layout:
//   ints:  [0,N) counts(deg)/cursor | [N,2N+1) row_ptr | [2N+16,+E) col
//          | [WS_PART,+128) partials
//   bytes: WB_BYTE  weights bf16 (self 65536, neigh 65536 ushorts)
//          FB_BYTE  feat bf16 (N*256)       [LARGE & XL]
//          HB2_BYTE H bf16   (N*256)        [XL]
// ---------------------------------------------------------------------------
#define WS_COUNTS 0
#define WS_ROWPTR (N_NODES)
#define WS_COL    (2 * N_NODES + 16)
#define WS_PART   (WS_COL + N_EDGES)
#define WB_BYTE   ((size_t)(WS_PART + 128) * 4)            // 7,200,576
#define FB_BYTE   (WB_BYTE + 2 * 65536 * 2)                // 7,462,720
#define FB_SZ     ((size_t)N_NODES * D * 2)                // 51,200,000
#define HB2_BYTE  (FB_BYTE + FB_SZ)
#define NEED_LARGE (FB_BYTE + FB_SZ)                       // 58.66 MB
#define NEED_XL    (HB2_BYTE + FB_SZ)                      // 109.9 MB
#define NEED_MID   (FB_BYTE)                               // 7.46 MB

#define EBLOCKS ((N_EDGES + 255) / 256)     // 6250
#define FBLOCKS (N_NODES * D / 8 / 256)     // 12500 (exact)
#define SCAN_NB ((N_NODES + 1023) / 1024)   // 98

// ---------------------------------------------------------------------------
// Fused cvt (feat + weights -> bf16) + hist, one launch.
// ---------------------------------------------------------------------------
__global__ __launch_bounds__(256) void cvt_hist_kernel(
    const float* __restrict__ feat, const float* __restrict__ w_self,
    const float* __restrict__ w_neigh, const int* __restrict__ dst,
    unsigned short* __restrict__ fb, unsigned short* __restrict__ wb,
    int* __restrict__ counts)
{
    const int b = blockIdx.x;
    if (b < FBLOCKS) {
        const int i = b * 256 + threadIdx.x;           // 8 elems each
        const f32x8 v = ((const f32x8*)feat)[i];
        ushort4 a, c;
        a.x = f2bf(v[0]); a.y = f2bf(v[1]); a.z = f2bf(v[2]); a.w = f2bf(v[3]);
        c.x = f2bf(v[4]); c.y = f2bf(v[5]); c.z = f2bf(v[6]); c.w = f2bf(v[7]);
        ((ushort4*)fb)[i * 2 + 0] = a;
        ((ushort4*)fb)[i * 2 + 1] = c;
    } else if (b < FBLOCKS + 128) {
        const int i = (b - FBLOCKS) * 256 + threadIdx.x;   // 0..32767, 4 each
        const bool isself = (i < 16384);
        const float* srcp = isself ? w_self : w_neigh;
        const int j = (isself ? i : i - 16384) * 4;
        const float4 v = *(const float4*)(srcp + j);
        ushort4 o;
        o.x = f2bf(v.x); o.y = f2bf(v.y); o.z = f2bf(v.z); o.w = f2bf(v.w);
        ((ushort4*)wb)[i] = o;
    } else {
        const int i = (b - FBLOCKS - 128) * 256 + threadIdx.x;
        if (i < N_EDGES) atomicAdd(&counts[dst[i]], 1);
    }
}

// ---- weights-only cvt + hist (MID/no-fb tiers) -----------------------------
__global__ __launch_bounds__(256) void wcvt_hist_kernel(
    const float* __restrict__ w_self, const float* __restrict__ w_neigh,
    const int* __restrict__ dst, unsigned short* __restrict__ wb,
    int* __restrict__ counts)
{
    const int b = blockIdx.x;
    if (b < 128) {
        const int i = b * 256 + threadIdx.x;
        const bool isself = (i < 16384);
        const float* srcp = isself ? w_self : w_neigh;
        const int j = (isself ? i : i - 16384) * 4;
        const float4 v = *(const float4*)(srcp + j);
        ushort4 o;
        o.x = f2bf(v.x); o.y = f2bf(v.y); o.z = f2bf(v.z); o.w = f2bf(v.w);
        ((ushort4*)wb)[i] = o;
    } else {
        const int i = (b - 128) * 256 + threadIdx.x;
        if (i < N_EDGES) atomicAdd(&counts[dst[i]], 1);
    }
}

// ---- 2-phase scan ----------------------------------------------------------
__global__ __launch_bounds__(1024) void scan_block_kernel(
    const int* __restrict__ counts, int* __restrict__ row_ptr,
    int* __restrict__ partials)
{
    __shared__ int wsum[16];
    const int t = threadIdx.x, b = blockIdx.x, i = b * 1024 + t;
    const int lane = t & 63, w = t >> 6;
    int x = (i < N_NODES) ? counts[i] : 0;
#pragma unroll
    for (int off = 1; off < 64; off <<= 1) {
        int y = __shfl_up(x, off, 64);
        if (lane >= off) x += y;
    }
    if (lane == 63) wsum[w] = x;
    __syncthreads();
    if (w == 0) {
        int s = (lane < 16) ? wsum[lane] : 0;
#pragma unroll
        for (int off = 1; off < 16; off <<= 1) {
            int y = __shfl_up(s, off, 64);
            if (lane >= off) s += y;
        }
        if (lane < 16) wsum[lane] = s;
    }
    __syncthreads();
    const int incl = x + (w > 0 ? wsum[w - 1] : 0);
    if (i < N_NODES) row_ptr[i + 1] = incl;        // block-local inclusive
    if (t == 1023) partials[b] = incl;             // block total (raw)
}

// Each block recomputes the exclusive prefix of partials locally (98 entries).
__global__ __launch_bounds__(1024) void scan_add2_kernel(
    const int* __restrict__ partials, int* __restrict__ row_ptr)
{
    __shared__ int sp[SCAN_NB];
    const int t = threadIdx.x, b = blockIdx.x;
    if (t < SCAN_NB) sp[t] = partials[t];
    __syncthreads();
    int off = 0;
    for (int j = 0; j < b; ++j) off += sp[j];      // uniform LDS broadcast
    const int i = b * 1024 + t;
    if (i < N_NODES) row_ptr[i + 1] += off;
    if (b == 0 && t == 0) row_ptr[0] = 0;
}

// ---- fill: consume leftover degree counts via atomicSub (no cursor memset)
__global__ __launch_bounds__(256) void fill_kernel(
    const int* __restrict__ src, const int* __restrict__ dst,
    const int* __restrict__ row_ptr, int* __restrict__ counts,
    int* __restrict__ col)
{
    const int i = blockIdx.x * 256 + threadIdx.x;
    if (i < N_EDGES) {
        const int d = dst[i];
        const int pos = atomicSub(&counts[d], 1) - 1;   // deg-1 .. 0
        col[row_ptr[d] + pos] = src[i];
    }
}

// ---- pull aggregation: one wave per node, bf16 rows, 16B/lane --------------
template <bool OUTBF16>
__global__ __launch_bounds__(256) void aggregate2_kernel(
    const unsigned short* __restrict__ featb,
    const int* __restrict__ row_ptr, const int* __restrict__ col,
    float* __restrict__ outf, unsigned short* __restrict__ outb)
{
    const int node = (blockIdx.x * blockDim.x + threadIdx.x) >> 6;
    const int lane = threadIdx.x & 63;
    if (node >= N_NODES) return;
    const int beg = row_ptr[node], end = row_ptr[node + 1];
    const int half = lane >> 5;
    const int chunk = lane & 31;

    float a0[8] = {0,0,0,0,0,0,0,0};
    float a1[8] = {0,0,0,0,0,0,0,0};
    float a2[8] = {0,0,0,0,0,0,0,0};
    float a3[8] = {0,0,0,0,0,0,0,0};

    const unsigned short* fbp = featb + chunk * 8;

    int j = beg + half;
    for (; j + 6 < end; j += 8) {
        const int s0 = col[j], s1 = col[j + 2], s2 = col[j + 4], s3 = col[j + 6];
        const u16x8 u0 = *(const u16x8*)(fbp + (size_t)s0 * D);
        const u16x8 u1 = *(const u16x8*)(fbp + (size_t)s1 * D);
        const u16x8 u2 = *(const u16x8*)(fbp + (size_t)s2 * D);
        const u16x8 u3 = *(const u16x8*)(fbp + (size_t)s3 * D);
#pragma unroll
        for (int i = 0; i < 8; ++i) a0[i] += bf2f(u0[i]);
#pragma unroll
        for (int i = 0; i < 8; ++i) a1[i] += bf2f(u1[i]);
#pragma unroll
        for (int i = 0; i < 8; ++i) a2[i] += bf2f(u2[i]);
#pragma unroll
        for (int i = 0; i < 8; ++i) a3[i] += bf2f(u3[i]);
    }
    for (; j < end; j += 2) {
        const int s0 = col[j];
        const u16x8 u0 = *(const u16x8*)(fbp + (size_t)s0 * D);
#pragma unroll
        for (int i = 0; i < 8; ++i) a0[i] += bf2f(u0[i]);
    }

    const float invd = 1.0f / fmaxf((float)(end - beg), 1.0f);
    float t[8];
#pragma unroll
    for (int i = 0; i < 8; ++i) {
        float v = (a0[i] + a1[i]) + (a2[i] + a3[i]);
        v += __shfl_xor(v, 32, 64);
        t[i] = v * invd;
    }

    if (OUTBF16) {
        if (half == 0) {
            u16x8 o;
#pragma unroll
            for (int i = 0; i < 8; ++i) o[i] = f2bf(t[i]);
            *(u16x8*)(outb + (size_t)node * D + chunk * 8) = o;
        }
    } else {
        float4 o;
        o.x = t[half * 4 + 0]; o.y = t[half * 4 + 1];
        o.z = t[half * 4 + 2]; o.w = t[half * 4 + 3];
        *(float4*)(outf + (size_t)node * D + chunk * 8 + half * 4) = o;
    }
}

// ---------------------------------------------------------------------------
// GEMM v2: 64x64 tile/wave, register double-buffered K pipeline.
// Block = 4 waves = 64 rows x 256 cols.  16 K-steps (K=512 virtual), each:
// prefetch next step's 4 A + 4 B frags, then 16 MFMAs (setprio-wrapped).
// A-self from fb, A-neigh from hb (both bf16 ws buffers); B from wb (L2-hot).
// No barriers; no output aliasing (XL tier).
// ---------------------------------------------------------------------------
__global__ __launch_bounds__(256) void gemm_v2_kernel(
    const unsigned short* __restrict__ fb,
    const unsigned short* __restrict__ hb,
    const unsigned short* __restrict__ wb,     // self @0, neigh @+65536
    const float* __restrict__ b_self,
    float* __restrict__ outp)
{
    const int lane = threadIdx.x & 63;
    const int wid  = threadIdx.x >> 6;
    const int row0 = blockIdx.x * 64;
    const int c0 = wid * 64;
    const int nl = lane & 15;
    const int kg = lane >> 4;

    f32x4 acc[4][4];
#pragma unroll
    for (int m = 0; m < 4; ++m)
#pragma unroll
        for (int n = 0; n < 4; ++n) acc[m][n] = (f32x4){0.f, 0.f, 0.f, 0.f};

    size_t aoff[4];
#pragma unroll
    for (int m = 0; m < 4; ++m) {
        int r = row0 + m * 16 + nl;
        if (r > N_NODES - 1) r = N_NODES - 1;
        aoff[m] = (size_t)r * D + kg * 8;
    }
    const int wcoff = (c0 + nl) * 256 + kg * 8;

#define LOADK(areg, breg, st) do {                                            \
        const unsigned short* ap_ = ((st) < 8) ? fb : hb;                     \
        const int kb_ = ((st) & 7) * 32;                                      \
        _Pragma("unroll") for (int m_ = 0; m_ < 4; ++m_)                      \
            areg[m_] = *(const s16x8*)(ap_ + aoff[m_] + kb_);                 \
        const unsigned short* wh_ = wb + ((st) < 8 ? 0 : 65536) + wcoff + kb_;\
        _Pragma("unroll") for (int n_ = 0; n_ < 4; ++n_)                      \
            breg[n_] = *(const s16x8*)(wh_ + n_ * 4096);                      \
    } while (0)

#define MFMAS(areg, breg) do {                                                \
        __builtin_amdgcn_s_setprio(1);                                        \
        _Pragma("unroll") for (int m_ = 0; m_ < 4; ++m_)                      \
        _Pragma("unroll") for (int n_ = 0; n_ < 4; ++n_)                      \
            acc[m_][n_] = __builtin_amdgcn_mfma_f32_16x16x32_bf16(            \
                areg[m_], breg[n_], acc[m_][n_], 0, 0, 0);                    \
        __builtin_amdgcn_s_setprio(0);                                        \
    } while (0)

    s16x8 aP[4], bP[4], aQ[4], bQ[4];
    LOADK(aP, bP, 0);
#pragma unroll
    for (int st = 0; st < 16; ++st) {
        if ((st & 1) == 0) {
            if (st < 15) LOADK(aQ, bQ, st + 1);
            MFMAS(aP, bP);
        } else {
            if (st < 15) LOADK(aP, bP, st + 1);
            MFMAS(aQ, bQ);
        }
    }
#undef LOADK
#undef MFMAS

#pragma unroll
    for (int n = 0; n < 4; ++n) {
        const float bias = b_self[c0 + n * 16 + nl];
#pragma unroll
        for (int m = 0; m < 4; ++m) {
            const int rbase = row0 + m * 16 + kg * 4;
#pragma unroll
            for (int r = 0; r < 4; ++r) {
                const int row = rbase + r;
                if (row < N_NODES)
                    outp[(size_t)row * D + c0 + n * 16 + nl] = acc[m][n][r] + bias;
            }
        }
    }
}

// ---------------------------------------------------------------------------
// MID tier: fp32 gather + in-place bf16 GEMM (H fp32 in out, own-rows only)
// ---------------------------------------------------------------------------
__global__ __launch_bounds__(256) void aggregate_f32_kernel(
    const float* __restrict__ feat, const int* __restrict__ row_ptr,
    const int* __restrict__ col, float* __restrict__ outf)
{
    const int node = (blockIdx.x * blockDim.x + threadIdx.x) >> 6;
    const int lane = threadIdx.x & 63;
    if (node >= N_NODES) return;
    const int beg = row_ptr[node], end = row_ptr[node + 1];

    float4 a0 = make_float4(0.f, 0.f, 0.f, 0.f);
    float4 a1 = make_float4(0.f, 0.f, 0.f, 0.f);
    float4 a2 = make_float4(0.f, 0.f, 0.f, 0.f);
    float4 a3 = make_float4(0.f, 0.f, 0.f, 0.f);

#define ACC(acc, s)                                                          \
    do {                                                                     \
        const float4 v = ((const float4*)(feat + (size_t)(s) * D))[lane];    \
        acc.x += v.x; acc.y += v.y; acc.z += v.z; acc.w += v.w;              \
    } while (0)

    int j = beg;
    for (; j + 3 < end; j += 4) {
        const int s0 = col[j], s1 = col[j + 1], s2 = col[j + 2], s3 = col[j + 3];
        ACC(a0, s0); ACC(a1, s1); ACC(a2, s2); ACC(a3, s3);
    }
    for (; j < end; ++j) { const int s0 = col[j]; ACC(a0, s0); }
#undef ACC

    const float invd = 1.0f / fmaxf((float)(end - beg), 1.0f);
    float4 r;
    r.x = ((a0.x + a1.x) + (a2.x + a3.x)) * invd;
    r.y = ((a0.y + a1.y) + (a2.y + a3.y)) * invd;
    r.z = ((a0.z + a1.z) + (a2.z + a3.z)) * invd;
    r.w = ((a0.w + a1.w) + (a2.w + a3.w)) * invd;
    ((float4*)(outf + (size_t)node * D))[lane] = r;
}

__global__ __launch_bounds__(256) void gemm_mfma64_f32h_kernel(
    const float* __restrict__ feat,
    const unsigned short* __restrict__ wb,
    const float* __restrict__ b_self,
    const float* h32,                      // aliases outp (in-place)
    float* outp)
{
    const int lane = threadIdx.x & 63;
    const int wslice = threadIdx.x >> 6;
    const int row0 = blockIdx.x * 64;
    const int c0 = wslice * 64;
    const int nl = lane & 15;
    const int kg = lane >> 4;

    f32x4 acc[4][4];
#pragma unroll
    for (int m = 0; m < 4; ++m)
#pragma unroll
        for (int n = 0; n < 4; ++n) acc[m][n] = (f32x4){0.f, 0.f, 0.f, 0.f};

    size_t aoff[4];
#pragma unroll
    for (int m = 0; m < 4; ++m) {
        int r = row0 + m * 16 + nl;
        if (r > N_NODES - 1) r = N_NODES - 1;
        aoff[m] = (size_t)r * D + kg * 8;
    }

#pragma unroll
    for (int hf = 0; hf < 2; ++hf) {
        const unsigned short* wh = wb + hf * 65536 + (size_t)(c0 + nl) * 256 + kg * 8;
#pragma unroll
        for (int kk = 0; kk < 8; ++kk) {
            const int kb = kk * 32;
            s16x8 afrag[4];
#pragma unroll
            for (int m = 0; m < 4; ++m) {
                const float* ap = hf == 0 ? (const float*)feat : h32;
                const f32x8 av = *(const f32x8*)(ap + aoff[m] + kb);
#pragma unroll
                for (int i = 0; i < 8; ++i) afrag[m][i] = (short)f2bf(av[i]);
            }
            s16x8 bfrag[4];
#pragma unroll
            for (int n = 0; n < 4; ++n)
                bfrag[n] = *(const s16x8*)(wh + n * 4096 + kb);
#pragma unroll
            for (int m = 0; m < 4; ++m)
#pragma unroll
                for (int n = 0; n < 4; ++n)
                    acc[m][n] = __builtin_amdgcn_mfma_f32_16x16x32_bf16(
                        afrag[m], bfrag[n], acc[m][n], 0, 0, 0);
        }
    }

    __syncthreads();   // in-place: reads of out rows done before stores

#pragma unroll
    for (int n = 0; n < 4; ++n) {
        const float bias = b_self[c0 + n * 16 + nl];
#pragma unroll
        for (int m = 0; m < 4; ++m) {
            const int rbase = row0 + m * 16 + kg * 4;
#pragma unroll
            for (int r = 0; r < 4; ++r) {
                const int row = rbase + r;
                if (row < N_NODES)
                    outp[(size_t)row * D + c0 + n * 16 + nl] = acc[m][n][r] + bias;
            }
        }
    }
}

// ---------------------------------------------------------------------------
// Atomic fallback path (tiny ws)
// ---------------------------------------------------------------------------
__global__ __launch_bounds__(256) void scatter_kernel(
    const float* __restrict__ feat, const int* __restrict__ src,
    const int* __restrict__ dst, float* __restrict__ S, float* __restrict__ deg)
{
    const int gtid = blockIdx.x * blockDim.x + threadIdx.x;
    const int wave = gtid >> 6;
    const int lane = gtid & 63;
    const int nwaves = (gridDim.x * blockDim.x) >> 6;
    for (int e = wave; e < N_EDGES; e += nwaves) {
        const int s = src[e];
        const int d = dst[e];
        if (lane == 0) unsafeAtomicAdd(&deg[d], 1.0f);
        const float4 v = ((const float4*)(feat + (size_t)s * D))[lane];
        float* o = S + (size_t)d * D + lane * 4;
        unsafeAtomicAdd(o + 0, v.x);
        unsafeAtomicAdd(o + 1, v.y);
        unsafeAtomicAdd(o + 2, v.z);
        unsafeAtomicAdd(o + 3, v.w);
    }
}

#define BM 64
#define BK 16

__global__ __launch_bounds__(256) void fused_gemm_f32(
    const float* __restrict__ feat, const float* __restrict__ w_neigh,
    const float* __restrict__ w_self, const float* __restrict__ b_self,
    const float* __restrict__ deg, float* out)
{
    __shared__ float At[BK][BM + 4];
    __shared__ float Bt[BK][256];

    const int tid = threadIdx.x;
    const int i0 = blockIdx.x * BM;
    const int trow = tid >> 4;
    const int tcol = tid & 15;
    const int m_load = tid >> 2;
    const int kq = tid & 3;

    const int arow = i0 + m_load;
    const bool arow_ok = arow < N_NODES;
    float invd = 1.0f;
    if (arow_ok) invd = 1.0f / fmaxf(deg[arow], 1.0f);

    float acc[4][16];
#pragma unroll
    for (int r = 0; r < 4; ++r)
#pragma unroll
        for (int c = 0; c < 16; ++c) acc[r][c] = 0.0f;

    for (int kc = 0; kc < (2 * D) / BK; ++kc) {
        const int kb = kc * BK;
        const bool self_part = (kb < D);
        const int kbase = self_part ? kb : (kb - D);

        float4 va = make_float4(0.f, 0.f, 0.f, 0.f);
        if (arow_ok) {
            const float* ap = self_part ? feat : out;
            va = *(const float4*)(ap + (size_t)arow * D + kbase + kq * 4);
            if (!self_part) { va.x *= invd; va.y *= invd; va.z *= invd; va.w *= invd; }
        }
        const float* W = self_part ? w_self : w_neigh;
        const float4* wp = (const float4*)(W + (size_t)tid * D + kbase);
        const float4 w0 = wp[0], w1 = wp[1], w2 = wp[2], w3 = wp[3];

        __syncthreads();
        At[kq * 4 + 0][m_load] = va.x;
        At[kq * 4 + 1][m_load] = va.y;
        At[kq * 4 + 2][m_load] = va.z;
        At[kq * 4 + 3][m_load] = va.w;
        Bt[ 0][tid] = w0.x; Bt[ 1][tid] = w0.y; Bt[ 2][tid] = w0.z; Bt[ 3][tid] = w0.w;
        Bt[ 4][tid] = w1.x; Bt[ 5][tid] = w1.y; Bt[ 6][tid] = w1.z; Bt[ 7][tid] = w1.w;
        Bt[ 8][tid] = w2.x; Bt[ 9][tid] = w2.y; Bt[10][tid] = w2.z; Bt[11][tid] = w2.w;
        Bt[12][tid] = w3.x; Bt[13][tid] = w3.y; Bt[14][tid] = w3.z; Bt[15][tid] = w3.w;
        __syncthreads();

#pragma unroll
        for (int k = 0; k < BK; ++k) {
            const float4 a = *(const float4*)&At[k][trow * 4];
            float4 b[4];
#pragma unroll
            for (int g = 0; g < 4; ++g)
                b[g] = *(const float4*)&Bt[k][g * 64 + tcol * 4];
            const float av[4] = {a.x, a.y, a.z, a.w};
#pragma unroll
            for (int r = 0; r < 4; ++r)
#pragma unroll
                for (int g = 0; g < 4; ++g) {
                    acc[r][g * 4 + 0] = fmaf(av[r], b[g].x, acc[r][g * 4 + 0]);
                    acc[r][g * 4 + 1] = fmaf(av[r], b[g].y, acc[r][g * 4 + 1]);
                    acc[r][g * 4 + 2] = fmaf(av[r], b[g].z, acc[r][g * 4 + 2]);
                    acc[r][g * 4 + 3] = fmaf(av[r], b[g].w, acc[r][g * 4 + 3]);
                }
        }
    }

    float4 bias[4];
#pragma unroll
    for (int g = 0; g < 4; ++g)
        bias[g] = *(const float4*)&b_self[g * 64 + tcol * 4];

#pragma unroll
    for (int r = 0; r < 4; ++r) {
        const int row = i0 + trow * 4 + r;
        if (row < N_NODES) {
            float* op = out + (size_t)row * D;
#pragma unroll
            for (int g = 0; g < 4; ++g) {
                float4 v;
                v.x = acc[r][g * 4 + 0] + bias[g].x;
                v.y = acc[r][g * 4 + 1] + bias[g].y;
                v.z = acc[r][g * 4 + 2] + bias[g].z;
                v.w = acc[r][g * 4 + 3] + bias[g].w;
                *(float4*)(op + g * 64 + tcol * 4) = v;
            }
        }
    }
}

// ---------------------------------------------------------------------------
extern "C" void kernel_launch(void* const* d_in, const int* in_sizes, int n_in,
                              void* d_out, int out_size, void* d_ws, size_t ws_size,
                              hipStream_t stream) {
    const float* feat    = (const float*)d_in[0];
    const int*   src     = (const int*)d_in[1];
    const int*   dst     = (const int*)d_in[2];
    const float* w_neigh = (const float*)d_in[3];
    const float* w_self  = (const float*)d_in[4];
    const float* b_self  = (const float*)d_in[5];
    float* out = (float*)d_out;

    const int ablocks = (N_NODES * 64 + 255) / 256;        // 1 wave/node
    const int gblocks = (N_NODES + 63) / 64;               // 64 rows/block

    if (ws_size >= NEED_MID) {
        int* wsI     = (int*)d_ws;
        int* counts  = wsI + WS_COUNTS;
        int* row_ptr = wsI + WS_ROWPTR;
        int* col     = wsI + WS_COL;
        int* part    = wsI + WS_PART;
        unsigned short* wb = (unsigned short*)((char*)d_ws + WB_BYTE);
        unsigned short* fb = (unsigned short*)((char*)d_ws + FB_BYTE);
        unsigned short* hb = (unsigned short*)((char*)d_ws + HB2_BYTE);

        hipMemsetAsync(counts, 0, N_NODES * sizeof(int), stream);
        if (ws_size >= NEED_LARGE)
            cvt_hist_kernel<<<FBLOCKS + 128 + EBLOCKS, 256, 0, stream>>>(
                feat, w_self, w_neigh, dst, fb, wb, counts);
        else
            wcvt_hist_kernel<<<128 + EBLOCKS, 256, 0, stream>>>(
                w_self, w_neigh, dst, wb, counts);
        scan_block_kernel<<<SCAN_NB, 1024, 0, stream>>>(counts, row_ptr, part);
        scan_add2_kernel<<<SCAN_NB, 1024, 0, stream>>>(part, row_ptr);
        fill_kernel<<<EBLOCKS, 256, 0, stream>>>(src, dst, row_ptr, counts, col);

        if (ws_size >= NEED_XL) {
            aggregate2_kernel<true><<<ablocks, 256, 0, stream>>>(
                fb, row_ptr, col, nullptr, hb);
            gemm_v2_kernel<<<gblocks, 256, 0, stream>>>(fb, hb, wb, b_self, out);
        } else if (ws_size >= NEED_LARGE) {
            aggregate2_kernel<false><<<ablocks, 256, 0, stream>>>(
                fb, row_ptr, col, out, nullptr);
            gemm_mfma64_f32h_kernel<<<gblocks, 256, 0, stream>>>(
                feat, wb, b_self, out, out);
        } else {
            aggregate_f32_kernel<<<ablocks, 256, 0, stream>>>(
                feat, row_ptr, col, out);
            gemm_mfma64_f32h_kernel<<<gblocks, 256, 0, stream>>>(
                feat, wb, b_self, out, out);
        }
    } else {
        float* deg = (float*)d_ws;
        hipMemsetAsync(out, 0, (size_t)N_NODES * D * sizeof(float), stream);
        hipMemsetAsync(deg, 0, (size_t)N_NODES * sizeof(float), stream);
        scatter_kernel<<<4096, 256, 0, stream>>>(feat, src, dst, out, deg);
        fused_gemm_f32<<<(N_NODES + BM - 1) / BM, 256, 0, stream>>>(
            feat, w_neigh, w_self, b_self, deg, out);
    }
}

// Round 10
// 422.246 us; speedup vs baseline: 1.0675x; 1.0675x over previous
//
#include <hip/hip_runtime.h>
#include <cstddef>

#define N_NODES 100000
#define N_EDGES 1600000
#define D 256

typedef short          s16x8 __attribute__((ext_vector_type(8)));
typedef unsigned short u16x8 __attribute__((ext_vector_type(8)));
typedef float          f32x4 __attribute__((ext_vector_type(4)));
typedef float          f32x8 __attribute__((ext_vector_type(8)));

__device__ __forceinline__ unsigned short f2bf(float f) {
    unsigned int u = __float_as_uint(f);
    unsigned int r = (u + 0x7fffu + ((u >> 16) & 1u)) >> 16;   // RNE
    return (unsigned short)r;
}
__device__ __forceinline__ float bf2f(unsigned short u) {
    return __uint_as_float(((unsigned int)u) << 16);
}

// ---------------------------------------------------------------------------
// Workspace layout:
//   ints:  [0,N) counts(deg)/cursor | [N,2N+1) row_ptr | [2N+16,+E) col
//          | [WS_PART,+128) partials
//   bytes: WB_BYTE  weights bf16 (self 65536, neigh 65536 ushorts)
//          FB_BYTE  feat bf16 (N*256)       [LARGE & XL]
//          HB2_BYTE H bf16   (N*256)        [XL]
// ---------------------------------------------------------------------------
#define WS_COUNTS 0
#define WS_ROWPTR (N_NODES)
#define WS_COL    (2 * N_NODES + 16)
#define WS_PART   (WS_COL + N_EDGES)
#define WB_BYTE   ((size_t)(WS_PART + 128) * 4)            // 7,200,576
#define FB_BYTE   (WB_BYTE + 2 * 65536 * 2)                // 7,462,720
#define FB_SZ     ((size_t)N_NODES * D * 2)                // 51,200,000
#define HB2_BYTE  (FB_BYTE + FB_SZ)
#define NEED_LARGE (FB_BYTE + FB_SZ)                       // 58.66 MB
#define NEED_XL    (HB2_BYTE + FB_SZ)                      // 109.9 MB
#define NEED_MID   (FB_BYTE)                               // 7.46 MB

#define EBLOCKS ((N_EDGES + 255) / 256)     // 6250
#define FBLOCKS (N_NODES * D / 8 / 256)     // 12500 (exact)
#define SCAN_NB ((N_NODES + 1023) / 1024)   // 98

// ---------------------------------------------------------------------------
// Fused cvt (feat + weights -> bf16) + hist, one launch.
// ---------------------------------------------------------------------------
__global__ __launch_bounds__(256) void cvt_hist_kernel(
    const float* __restrict__ feat, const float* __restrict__ w_self,
    const float* __restrict__ w_neigh, const int* __restrict__ dst,
    unsigned short* __restrict__ fb, unsigned short* __restrict__ wb,
    int* __restrict__ counts)
{
    const int b = blockIdx.x;
    if (b < FBLOCKS) {
        const int i = b * 256 + threadIdx.x;           // 8 elems each
        const f32x8 v = ((const f32x8*)feat)[i];
        ushort4 a, c;
        a.x = f2bf(v[0]); a.y = f2bf(v[1]); a.z = f2bf(v[2]); a.w = f2bf(v[3]);
        c.x = f2bf(v[4]); c.y = f2bf(v[5]); c.z = f2bf(v[6]); c.w = f2bf(v[7]);
        ((ushort4*)fb)[i * 2 + 0] = a;
        ((ushort4*)fb)[i * 2 + 1] = c;
    } else if (b < FBLOCKS + 128) {
        const int i = (b - FBLOCKS) * 256 + threadIdx.x;   // 0..32767, 4 each
        const bool isself = (i < 16384);
        const float* srcp = isself ? w_self : w_neigh;
        const int j = (isself ? i : i - 16384) * 4;
        const float4 v = *(const float4*)(srcp + j);
        ushort4 o;
        o.x = f2bf(v.x); o.y = f2bf(v.y); o.z = f2bf(v.z); o.w = f2bf(v.w);
        ((ushort4*)wb)[i] = o;
    } else {
        const int i = (b - FBLOCKS - 128) * 256 + threadIdx.x;
        if (i < N_EDGES) atomicAdd(&counts[dst[i]], 1);
    }
}

// ---- weights-only cvt + hist (MID tier) ------------------------------------
__global__ __launch_bounds__(256) void wcvt_hist_kernel(
    const float* __restrict__ w_self, const float* __restrict__ w_neigh,
    const int* __restrict__ dst, unsigned short* __restrict__ wb,
    int* __restrict__ counts)
{
    const int b = blockIdx.x;
    if (b < 128) {
        const int i = b * 256 + threadIdx.x;
        const bool isself = (i < 16384);
        const float* srcp = isself ? w_self : w_neigh;
        const int j = (isself ? i : i - 16384) * 4;
        const float4 v = *(const float4*)(srcp + j);
        ushort4 o;
        o.x = f2bf(v.x); o.y = f2bf(v.y); o.z = f2bf(v.z); o.w = f2bf(v.w);
        ((ushort4*)wb)[i] = o;
    } else {
        const int i = (b - 128) * 256 + threadIdx.x;
        if (i < N_EDGES) atomicAdd(&counts[dst[i]], 1);
    }
}

// ---- 2-phase scan ----------------------------------------------------------
__global__ __launch_bounds__(1024) void scan_block_kernel(
    const int* __restrict__ counts, int* __restrict__ row_ptr,
    int* __restrict__ partials)
{
    __shared__ int wsum[16];
    const int t = threadIdx.x, b = blockIdx.x, i = b * 1024 + t;
    const int lane = t & 63, w = t >> 6;
    int x = (i < N_NODES) ? counts[i] : 0;
#pragma unroll
    for (int off = 1; off < 64; off <<= 1) {
        int y = __shfl_up(x, off, 64);
        if (lane >= off) x += y;
    }
    if (lane == 63) wsum[w] = x;
    __syncthreads();
    if (w == 0) {
        int s = (lane < 16) ? wsum[lane] : 0;
#pragma unroll
        for (int off = 1; off < 16; off <<= 1) {
            int y = __shfl_up(s, off, 64);
            if (lane >= off) s += y;
        }
        if (lane < 16) wsum[lane] = s;
    }
    __syncthreads();
    const int incl = x + (w > 0 ? wsum[w - 1] : 0);
    if (i < N_NODES) row_ptr[i + 1] = incl;
    if (t == 1023) partials[b] = incl;
}

__global__ __launch_bounds__(1024) void scan_add2_kernel(
    const int* __restrict__ partials, int* __restrict__ row_ptr)
{
    __shared__ int sp[SCAN_NB];
    const int t = threadIdx.x, b = blockIdx.x;
    if (t < SCAN_NB) sp[t] = partials[t];
    __syncthreads();
    int off = 0;
    for (int j = 0; j < b; ++j) off += sp[j];
    const int i = b * 1024 + t;
    if (i < N_NODES) row_ptr[i + 1] += off;
    if (b == 0 && t == 0) row_ptr[0] = 0;
}

// ---- fill: consume degree counts via atomicSub (no cursor memset) ----------
__global__ __launch_bounds__(256) void fill_kernel(
    const int* __restrict__ src, const int* __restrict__ dst,
    const int* __restrict__ row_ptr, int* __restrict__ counts,
    int* __restrict__ col)
{
    const int i = blockIdx.x * 256 + threadIdx.x;
    if (i < N_EDGES) {
        const int d = dst[i];
        const int pos = atomicSub(&counts[d], 1) - 1;
        col[row_ptr[d] + pos] = src[i];
    }
}

// ---- pull aggregation: one wave per node, bf16 rows, 16B/lane --------------
template <bool OUTBF16>
__global__ __launch_bounds__(256) void aggregate2_kernel(
    const unsigned short* __restrict__ featb,
    const int* __restrict__ row_ptr, const int* __restrict__ col,
    float* __restrict__ outf, unsigned short* __restrict__ outb)
{
    const int node = (blockIdx.x * blockDim.x + threadIdx.x) >> 6;
    const int lane = threadIdx.x & 63;
    if (node >= N_NODES) return;
    const int beg = row_ptr[node], end = row_ptr[node + 1];
    const int half = lane >> 5;
    const int chunk = lane & 31;

    float a0[8] = {0,0,0,0,0,0,0,0};
    float a1[8] = {0,0,0,0,0,0,0,0};
    float a2[8] = {0,0,0,0,0,0,0,0};
    float a3[8] = {0,0,0,0,0,0,0,0};

    const unsigned short* fbp = featb + chunk * 8;

    int j = beg + half;
    for (; j + 6 < end; j += 8) {
        const int s0 = col[j], s1 = col[j + 2], s2 = col[j + 4], s3 = col[j + 6];
        const u16x8 u0 = *(const u16x8*)(fbp + (size_t)s0 * D);
        const u16x8 u1 = *(const u16x8*)(fbp + (size_t)s1 * D);
        const u16x8 u2 = *(const u16x8*)(fbp + (size_t)s2 * D);
        const u16x8 u3 = *(const u16x8*)(fbp + (size_t)s3 * D);
#pragma unroll
        for (int i = 0; i < 8; ++i) a0[i] += bf2f(u0[i]);
#pragma unroll
        for (int i = 0; i < 8; ++i) a1[i] += bf2f(u1[i]);
#pragma unroll
        for (int i = 0; i < 8; ++i) a2[i] += bf2f(u2[i]);
#pragma unroll
        for (int i = 0; i < 8; ++i) a3[i] += bf2f(u3[i]);
    }
    for (; j < end; j += 2) {
        const int s0 = col[j];
        const u16x8 u0 = *(const u16x8*)(fbp + (size_t)s0 * D);
#pragma unroll
        for (int i = 0; i < 8; ++i) a0[i] += bf2f(u0[i]);
    }

    const float invd = 1.0f / fmaxf((float)(end - beg), 1.0f);
    float t[8];
#pragma unroll
    for (int i = 0; i < 8; ++i) {
        float v = (a0[i] + a1[i]) + (a2[i] + a3[i]);
        v += __shfl_xor(v, 32, 64);
        t[i] = v * invd;
    }

    if (OUTBF16) {
        if (half == 0) {
            u16x8 o;
#pragma unroll
            for (int i = 0; i < 8; ++i) o[i] = f2bf(t[i]);
            *(u16x8*)(outb + (size_t)node * D + chunk * 8) = o;
        }
    } else {
        float4 o;
        o.x = t[half * 4 + 0]; o.y = t[half * 4 + 1];
        o.z = t[half * 4 + 2]; o.w = t[half * 4 + 3];
        *(float4*)(outf + (size_t)node * D + chunk * 8 + half * 4) = o;
    }
}

// ---------------------------------------------------------------------------
// GEMM v3: LDS-staged 2-phase structure (T3 minimum recipe, reg-staged).
// Block = 256 thr = 4 waves; tile 128 rows x 128 cols (wave: 64x64).
// 8 K-steps of BK=64 (steps 0-3: fb/Ws, 4-7: hb/Wn).  Per step:
//   ds_write staged regs -> As (XOR-swizzled)  |  barrier
//   issue next step's global loads (ride under MFMA)  |  2x(4 ds_read +
//   4 B-loads + 16 MFMA)  |  barrier.
// Swizzle cs ^= (row&7)<<3 on BOTH write and read: 8 lanes/16B-slot even
// spread -> conflict-free.  B direct from wb (256 KB, L2-resident).
// ---------------------------------------------------------------------------
#define GBM 128
#define GBK 64   // shorts

__global__ __launch_bounds__(256) void gemm_v3_kernel(
    const unsigned short* __restrict__ fb,
    const unsigned short* __restrict__ hb,
    const unsigned short* __restrict__ wb,     // self @0, neigh @+65536
    const float* __restrict__ b_self,
    float* __restrict__ outp)
{
    __shared__ unsigned short As[GBM * GBK];   // 16 KB

    const int t    = threadIdx.x;
    const int lane = t & 63;
    const int w    = t >> 6;                   // 0..3
    const int wr   = w >> 1, wc = w & 1;
    const int row0 = (blockIdx.x >> 1) * GBM;
    const int c0   = (blockIdx.x & 1) * 128 + wc * 64;
    const int nl   = lane & 15;
    const int kg   = lane >> 4;

    // staging coords: thread t covers row tr, 64B half th (4x16B chunks)
    const int tr = t >> 1;
    const int th = t & 1;
    int grow = row0 + tr; if (grow > N_NODES - 1) grow = N_NODES - 1;
    const size_t gbrow = (size_t)grow * D;

    int wsw[4];
#pragma unroll
    for (int c = 0; c < 4; ++c) {
        const int cs = th * 32 + c * 8;                    // short col in [0,64)
        wsw[c] = tr * GBK + (cs ^ ((tr & 7) << 3));
    }
    int rsw[4][2];
#pragma unroll
    for (int m = 0; m < 4; ++m) {
        const int r = wr * 64 + m * 16 + nl;
#pragma unroll
        for (int kk = 0; kk < 2; ++kk) {
            const int cs = kg * 8 + kk * 32;
            rsw[m][kk] = r * GBK + (cs ^ ((r & 7) << 3));
        }
    }

    f32x4 acc[4][4];
#pragma unroll
    for (int m = 0; m < 4; ++m)
#pragma unroll
        for (int n = 0; n < 4; ++n) acc[m][n] = (f32x4){0.f, 0.f, 0.f, 0.f};

    u16x8 st[4];
#pragma unroll
    for (int c = 0; c < 4; ++c)
        st[c] = *(const u16x8*)(fb + gbrow + th * 32 + c * 8);

#pragma unroll
    for (int s = 0; s < 8; ++s) {
        // ---- write staged tile to LDS (swizzled) ----
#pragma unroll
        for (int c = 0; c < 4; ++c) *(u16x8*)&As[wsw[c]] = st[c];
        __syncthreads();

        // ---- issue next step's global loads (overlap with MFMA phase) ----
        if (s < 7) {
            const unsigned short* ap = (s + 1 < 4) ? fb : hb;
            const int koff = ((s + 1) & 3) * 64 + th * 32;
#pragma unroll
            for (int c = 0; c < 4; ++c)
                st[c] = *(const u16x8*)(ap + gbrow + koff + c * 8);
        }

        // ---- compute ----
        const int hsel = (s < 4) ? 0 : 65536;
        const int kbase = (s & 3) * 64;
#pragma unroll
        for (int kk = 0; kk < 2; ++kk) {
            s16x8 a[4], b[4];
#pragma unroll
            for (int m = 0; m < 4; ++m)
                a[m] = *(const s16x8*)&As[rsw[m][kk]];
#pragma unroll
            for (int n = 0; n < 4; ++n)
                b[n] = *(const s16x8*)(wb + hsel
                        + (size_t)(c0 + n * 16 + nl) * 256 + kbase + kk * 32 + kg * 8);
#pragma unroll
            for (int m = 0; m < 4; ++m)
#pragma unroll
                for (int n = 0; n < 4; ++n)
                    acc[m][n] = __builtin_amdgcn_mfma_f32_16x16x32_bf16(
                        a[m], b[n], acc[m][n], 0, 0, 0);
        }
        __syncthreads();
    }

#pragma unroll
    for (int n = 0; n < 4; ++n) {
        const float bias = b_self[c0 + n * 16 + nl];
#pragma unroll
        for (int m = 0; m < 4; ++m) {
            const int rbase = row0 + wr * 64 + m * 16 + kg * 4;
#pragma unroll
            for (int r = 0; r < 4; ++r) {
                const int row = rbase + r;
                if (row < N_NODES)
                    outp[(size_t)row * D + c0 + n * 16 + nl] = acc[m][n][r] + bias;
            }
        }
    }
}

// ---------------------------------------------------------------------------
// MID/LARGE tier: fp32-H in-place GEMM (reads own rows only; barrier before
// stores) + fp32/bf16 gather.
// ---------------------------------------------------------------------------
__global__ __launch_bounds__(256) void aggregate_f32_kernel(
    const float* __restrict__ feat, const int* __restrict__ row_ptr,
    const int* __restrict__ col, float* __restrict__ outf)
{
    const int node = (blockIdx.x * blockDim.x + threadIdx.x) >> 6;
    const int lane = threadIdx.x & 63;
    if (node >= N_NODES) return;
    const int beg = row_ptr[node], end = row_ptr[node + 1];

    float4 a0 = make_float4(0.f, 0.f, 0.f, 0.f);
    float4 a1 = make_float4(0.f, 0.f, 0.f, 0.f);
    float4 a2 = make_float4(0.f, 0.f, 0.f, 0.f);
    float4 a3 = make_float4(0.f, 0.f, 0.f, 0.f);

#define ACC(acc, s)                                                          \
    do {                                                                     \
        const float4 v = ((const float4*)(feat + (size_t)(s) * D))[lane];    \
        acc.x += v.x; acc.y += v.y; acc.z += v.z; acc.w += v.w;              \
    } while (0)

    int j = beg;
    for (; j + 3 < end; j += 4) {
        const int s0 = col[j], s1 = col[j + 1], s2 = col[j + 2], s3 = col[j + 3];
        ACC(a0, s0); ACC(a1, s1); ACC(a2, s2); ACC(a3, s3);
    }
    for (; j < end; ++j) { const int s0 = col[j]; ACC(a0, s0); }
#undef ACC

    const float invd = 1.0f / fmaxf((float)(end - beg), 1.0f);
    float4 r;
    r.x = ((a0.x + a1.x) + (a2.x + a3.x)) * invd;
    r.y = ((a0.y + a1.y) + (a2.y + a3.y)) * invd;
    r.z = ((a0.z + a1.z) + (a2.z + a3.z)) * invd;
    r.w = ((a0.w + a1.w) + (a2.w + a3.w)) * invd;
    ((float4*)(outf + (size_t)node * D))[lane] = r;
}

__global__ __launch_bounds__(256) void gemm_mfma64_f32h_kernel(
    const float* __restrict__ feat,
    const unsigned short* __restrict__ wb,
    const float* __restrict__ b_self,
    const float* h32,                      // aliases outp (in-place)
    float* outp)
{
    const int lane = threadIdx.x & 63;
    const int wslice = threadIdx.x >> 6;
    const int row0 = blockIdx.x * 64;
    const int c0 = wslice * 64;
    const int nl = lane & 15;
    const int kg = lane >> 4;

    f32x4 acc[4][4];
#pragma unroll
    for (int m = 0; m < 4; ++m)
#pragma unroll
        for (int n = 0; n < 4; ++n) acc[m][n] = (f32x4){0.f, 0.f, 0.f, 0.f};

    size_t aoff[4];
#pragma unroll
    for (int m = 0; m < 4; ++m) {
        int r = row0 + m * 16 + nl;
        if (r > N_NODES - 1) r = N_NODES - 1;
        aoff[m] = (size_t)r * D + kg * 8;
    }

#pragma unroll
    for (int hf = 0; hf < 2; ++hf) {
        const unsigned short* wh = wb + hf * 65536 + (size_t)(c0 + nl) * 256 + kg * 8;
#pragma unroll
        for (int kk = 0; kk < 8; ++kk) {
            const int kb = kk * 32;
            s16x8 afrag[4];
#pragma unroll
            for (int m = 0; m < 4; ++m) {
                const float* ap = hf == 0 ? (const float*)feat : h32;
                const f32x8 av = *(const f32x8*)(ap + aoff[m] + kb);
#pragma unroll
                for (int i = 0; i < 8; ++i) afrag[m][i] = (short)f2bf(av[i]);
            }
            s16x8 bfrag[4];
#pragma unroll
            for (int n = 0; n < 4; ++n)
                bfrag[n] = *(const s16x8*)(wh + n * 4096 + kb);
#pragma unroll
            for (int m = 0; m < 4; ++m)
#pragma unroll
                for (int n = 0; n < 4; ++n)
                    acc[m][n] = __builtin_amdgcn_mfma_f32_16x16x32_bf16(
                        afrag[m], bfrag[n], acc[m][n], 0, 0, 0);
        }
    }

    __syncthreads();

#pragma unroll
    for (int n = 0; n < 4; ++n) {
        const float bias = b_self[c0 + n * 16 + nl];
#pragma unroll
        for (int m = 0; m < 4; ++m) {
            const int rbase = row0 + m * 16 + kg * 4;
#pragma unroll
            for (int r = 0; r < 4; ++r) {
                const int row = rbase + r;
                if (row < N_NODES)
                    outp[(size_t)row * D + c0 + n * 16 + nl] = acc[m][n][r] + bias;
            }
        }
    }
}

// ---------------------------------------------------------------------------
// Atomic fallback path (tiny ws)
// ---------------------------------------------------------------------------
__global__ __launch_bounds__(256) void scatter_kernel(
    const float* __restrict__ feat, const int* __restrict__ src,
    const int* __restrict__ dst, float* __restrict__ S, float* __restrict__ deg)
{
    const int gtid = blockIdx.x * blockDim.x + threadIdx.x;
    const int wave = gtid >> 6;
    const int lane = gtid & 63;
    const int nwaves = (gridDim.x * blockDim.x) >> 6;
    for (int e = wave; e < N_EDGES; e += nwaves) {
        const int s = src[e];
        const int d = dst[e];
        if (lane == 0) unsafeAtomicAdd(&deg[d], 1.0f);
        const float4 v = ((const float4*)(feat + (size_t)s * D))[lane];
        float* o = S + (size_t)d * D + lane * 4;
        unsafeAtomicAdd(o + 0, v.x);
        unsafeAtomicAdd(o + 1, v.y);
        unsafeAtomicAdd(o + 2, v.z);
        unsafeAtomicAdd(o + 3, v.w);
    }
}

#define BM 64
#define BK 16

__global__ __launch_bounds__(256) void fused_gemm_f32(
    const float* __restrict__ feat, const float* __restrict__ w_neigh,
    const float* __restrict__ w_self, const float* __restrict__ b_self,
    const float* __restrict__ deg, float* out)
{
    __shared__ float At[BK][BM + 4];
    __shared__ float Bt[BK][256];

    const int tid = threadIdx.x;
    const int i0 = blockIdx.x * BM;
    const int trow = tid >> 4;
    const int tcol = tid & 15;
    const int m_load = tid >> 2;
    const int kq = tid & 3;

    const int arow = i0 + m_load;
    const bool arow_ok = arow < N_NODES;
    float invd = 1.0f;
    if (arow_ok) invd = 1.0f / fmaxf(deg[arow], 1.0f);

    float acc[4][16];
#pragma unroll
    for (int r = 0; r < 4; ++r)
#pragma unroll
        for (int c = 0; c < 16; ++c) acc[r][c] = 0.0f;

    for (int kc = 0; kc < (2 * D) / BK; ++kc) {
        const int kb = kc * BK;
        const bool self_part = (kb < D);
        const int kbase = self_part ? kb : (kb - D);

        float4 va = make_float4(0.f, 0.f, 0.f, 0.f);
        if (arow_ok) {
            const float* ap = self_part ? feat : out;
            va = *(const float4*)(ap + (size_t)arow * D + kbase + kq * 4);
            if (!self_part) { va.x *= invd; va.y *= invd; va.z *= invd; va.w *= invd; }
        }
        const float* W = self_part ? w_self : w_neigh;
        const float4* wp = (const float4*)(W + (size_t)tid * D + kbase);
        const float4 w0 = wp[0], w1 = wp[1], w2 = wp[2], w3 = wp[3];

        __syncthreads();
        At[kq * 4 + 0][m_load] = va.x;
        At[kq * 4 + 1][m_load] = va.y;
        At[kq * 4 + 2][m_load] = va.z;
        At[kq * 4 + 3][m_load] = va.w;
        Bt[ 0][tid] = w0.x; Bt[ 1][tid] = w0.y; Bt[ 2][tid] = w0.z; Bt[ 3][tid] = w0.w;
        Bt[ 4][tid] = w1.x; Bt[ 5][tid] = w1.y; Bt[ 6][tid] = w1.z; Bt[ 7][tid] = w1.w;
        Bt[ 8][tid] = w2.x; Bt[ 9][tid] = w2.y; Bt[10][tid] = w2.z; Bt[11][tid] = w2.w;
        Bt[12][tid] = w3.x; Bt[13][tid] = w3.y; Bt[14][tid] = w3.z; Bt[15][tid] = w3.w;
        __syncthreads();

#pragma unroll
        for (int k = 0; k < BK; ++k) {
            const float4 a = *(const float4*)&At[k][trow * 4];
            float4 b[4];
#pragma unroll
            for (int g = 0; g < 4; ++g)
                b[g] = *(const float4*)&Bt[k][g * 64 + tcol * 4];
            const float av[4] = {a.x, a.y, a.z, a.w};
#pragma unroll
            for (int r = 0; r < 4; ++r)
#pragma unroll
                for (int g = 0; g < 4; ++g) {
                    acc[r][g * 4 + 0] = fmaf(av[r], b[g].x, acc[r][g * 4 + 0]);
                    acc[r][g * 4 + 1] = fmaf(av[r], b[g].y, acc[r][g * 4 + 1]);
                    acc[r][g * 4 + 2] = fmaf(av[r], b[g].z, acc[r][g * 4 + 2]);
                    acc[r][g * 4 + 3] = fmaf(av[r], b[g].w, acc[r][g * 4 + 3]);
                }
        }
    }

    float4 bias[4];
#pragma unroll
    for (int g = 0; g < 4; ++g)
        bias[g] = *(const float4*)&b_self[g * 64 + tcol * 4];

#pragma unroll
    for (int r = 0; r < 4; ++r) {
        const int row = i0 + trow * 4 + r;
        if (row < N_NODES) {
            float* op = out + (size_t)row * D;
#pragma unroll
            for (int g = 0; g < 4; ++g) {
                float4 v;
                v.x = acc[r][g * 4 + 0] + bias[g].x;
                v.y = acc[r][g * 4 + 1] + bias[g].y;
                v.z = acc[r][g * 4 + 2] + bias[g].z;
                v.w = acc[r][g * 4 + 3] + bias[g].w;
                *(float4*)(op + g * 64 + tcol * 4) = v;
            }
        }
    }
}

// ---------------------------------------------------------------------------
extern "C" void kernel_launch(void* const* d_in, const int* in_sizes, int n_in,
                              void* d_out, int out_size, void* d_ws, size_t ws_size,
                              hipStream_t stream) {
    const float* feat    = (const float*)d_in[0];
    const int*   src     = (const int*)d_in[1];
    const int*   dst     = (const int*)d_in[2];
    const float* w_neigh = (const float*)d_in[3];
    const float* w_self  = (const float*)d_in[4];
    const float* b_self  = (const float*)d_in[5];
    float* out = (float*)d_out;

    const int ablocks  = (N_NODES * 64 + 255) / 256;       // 1 wave/node
    const int g64blks  = (N_NODES + 63) / 64;
    const int gv3blks  = ((N_NODES + GBM - 1) / GBM) * 2;  // 782 x 2 col-tiles

    if (ws_size >= NEED_MID) {
        int* wsI     = (int*)d_ws;
        int* counts  = wsI + WS_COUNTS;
        int* row_ptr = wsI + WS_ROWPTR;
        int* col     = wsI + WS_COL;
        int* part    = wsI + WS_PART;
        unsigned short* wb = (unsigned short*)((char*)d_ws + WB_BYTE);
        unsigned short* fb = (unsigned short*)((char*)d_ws + FB_BYTE);
        unsigned short* hb = (unsigned short*)((char*)d_ws + HB2_BYTE);

        hipMemsetAsync(counts, 0, N_NODES * sizeof(int), stream);
        if (ws_size >= NEED_LARGE)
            cvt_hist_kernel<<<FBLOCKS + 128 + EBLOCKS, 256, 0, stream>>>(
                feat, w_self, w_neigh, dst, fb, wb, counts);
        else
            wcvt_hist_kernel<<<128 + EBLOCKS, 256, 0, stream>>>(
                w_self, w_neigh, dst, wb, counts);
        scan_block_kernel<<<SCAN_NB, 1024, 0, stream>>>(counts, row_ptr, part);
        scan_add2_kernel<<<SCAN_NB, 1024, 0, stream>>>(part, row_ptr);
        fill_kernel<<<EBLOCKS, 256, 0, stream>>>(src, dst, row_ptr, counts, col);

        if (ws_size >= NEED_XL) {
            aggregate2_kernel<true><<<ablocks, 256, 0, stream>>>(
                fb, row_ptr, col, nullptr, hb);
            gemm_v3_kernel<<<gv3blks, 256, 0, stream>>>(fb, hb, wb, b_self, out);
        } else if (ws_size >= NEED_LARGE) {
            aggregate2_kernel<false><<<ablocks, 256, 0, stream>>>(
                fb, row_ptr, col, out, nullptr);
            gemm_mfma64_f32h_kernel<<<g64blks, 256, 0, stream>>>(
                feat, wb, b_self, out, out);
        } else {
            aggregate_f32_kernel<<<ablocks, 256, 0, stream>>>(
                feat, row_ptr, col, out);
            gemm_mfma64_f32h_kernel<<<g64blks, 256, 0, stream>>>(
                feat, wb, b_self, out, out);
        }
    } else {
        float* deg = (float*)d_ws;
        hipMemsetAsync(out, 0, (size_t)N_NODES * D * sizeof(float), stream);
        hipMemsetAsync(deg, 0, (size_t)N_NODES * sizeof(float), stream);
        scatter_kernel<<<4096, 256, 0, stream>>>(feat, src, dst, out, deg);
        fused_gemm_f32<<<(N_NODES + BM - 1) / BM, 256, 0, stream>>>(
            feat, w_neigh, w_self, b_self, deg, out);
    }
}